// Round 5
// baseline (32.601 us; speedup 1.0000x reference)
//
#include <hip/hip_runtime.h>

// out[i] = A_source[i] + b2 + sum_j W2[j] * tanh(W1[j][0]*c_target[i] + W1[j][1]*wavelength[i] + b1[j])
// (W1[j][2] multiplies a zero; c_source is unused by the reference.)
//
// tanh(z) = 1 - 2/(exp2(z*2/ln2)+1), folded:
//   s = (A + b2 + sum_j W2[j]) + sum_j (-2*W2[j]) * rcp(exp2(z')+1)
// One v_exp_f32 + one v_rcp_f32 per hidden unit.
//
// History: R1 45us (IEEE div VALU-bound) -> R2 28us (rcp) -> R4 29.8us
// (2x/thread + nontemporal store: NT regressed; harness fills 268MB between
// replays so every replay is HBM-cold -> floor = 128MB @ 6.3TB/s ~ 20.3us).
//
// Round 5: 4 float4/thread/stream (64B/lane contiguous bursts, 12 loads in
// flight), regular stores, exact grid (no bounds branch).

#define HGEO 8

__global__ __launch_bounds__(256) void geodesic_kernel(
    const float4* __restrict__ c_target,
    const float4* __restrict__ wavelength,
    const float4* __restrict__ A_source,
    const float* __restrict__ W1,   // [8][3] row-major
    const float* __restrict__ b1,   // [8]
    const float* __restrict__ W2,   // [8]
    const float* __restrict__ b2,   // [1]
    float4* __restrict__ out)
{
    const float K = 2.885390081777927f;  // 2/ln(2)

    float wa[HGEO], wb[HGEO], bb[HGEO], wo2[HGEO];
    float s0 = b2[0];
#pragma unroll
    for (int j = 0; j < HGEO; ++j) {
        wa[j]  = W1[j * 3 + 0] * K;
        wb[j]  = W1[j * 3 + 1] * K;
        bb[j]  = b1[j] * K;
        float wo = W2[j];
        wo2[j] = -2.0f * wo;
        s0 += wo;
    }

    const int base = (blockIdx.x * blockDim.x + threadIdx.x) * 4;

    // 64 B contiguous per lane per stream: 4 x global_load_dwordx4 each.
    float4 c[4], w[4], a[4];
#pragma unroll
    for (int q = 0; q < 4; ++q) c[q] = c_target[base + q];
#pragma unroll
    for (int q = 0; q < 4; ++q) w[q] = wavelength[base + q];
#pragma unroll
    for (int q = 0; q < 4; ++q) a[q] = A_source[base + q];

    float4 o[4];
#pragma unroll
    for (int q = 0; q < 4; ++q) {
        const float cv[4] = {c[q].x, c[q].y, c[q].z, c[q].w};
        const float wv[4] = {w[q].x, w[q].y, w[q].z, w[q].w};
        const float av[4] = {a[q].x, a[q].y, a[q].z, a[q].w};
        float ov[4];
#pragma unroll
        for (int k = 0; k < 4; ++k) {
            float s = av[k] + s0;
#pragma unroll
            for (int j = 0; j < HGEO; ++j) {
                float z = fmaf(wa[j], cv[k], fmaf(wb[j], wv[k], bb[j]));
                float e = exp2f(z);                        // one v_exp_f32
                float r = __builtin_amdgcn_rcpf(e + 1.0f); // one v_rcp_f32
                s = fmaf(wo2[j], r, s);
            }
            ov[k] = s;
        }
        o[q] = make_float4(ov[0], ov[1], ov[2], ov[3]);
    }

#pragma unroll
    for (int q = 0; q < 4; ++q) out[base + q] = o[q];
}

extern "C" void kernel_launch(void* const* d_in, const int* in_sizes, int n_in,
                              void* d_out, int out_size, void* d_ws, size_t ws_size,
                              hipStream_t stream) {
    // Input order per setup_inputs(): c_source, c_target, wavelength, A_source, W1, b1, W2, b2
    const float4* c_target   = (const float4*)d_in[1];
    const float4* wavelength = (const float4*)d_in[2];
    const float4* A_source   = (const float4*)d_in[3];
    const float*  W1 = (const float*)d_in[4];
    const float*  b1 = (const float*)d_in[5];
    const float*  W2 = (const float*)d_in[6];
    const float*  b2 = (const float*)d_in[7];
    float4* out = (float4*)d_out;

    const int n4 = out_size / 4;                 // 2097152 float4s
    const int threads = 256;
    const int blocks = n4 / (4 * threads);       // 2048 — exact, 4 float4/thread
    geodesic_kernel<<<blocks, threads, 0, stream>>>(
        c_target, wavelength, A_source, W1, b1, W2, b2, out);
}

// Round 6
// 27.870 us; speedup vs baseline: 1.1697x; 1.1697x over previous
//
#include <hip/hip_runtime.h>

// out[i] = A_source[i] + b2 + sum_j W2[j] * tanh(W1[j][0]*c_target[i] + W1[j][1]*wavelength[i] + b1[j])
// (W1[j][2] multiplies a zero; c_source is unused by the reference.)
//
// History: R1 45us (IEEE div, VALU-bound) -> R2 28us (exp2+rcp) -> R4/R5
// (more ILP/thread: 29.8/32.6us — TLP beats ILP, R2 structure is best).
// Calibration from R4 counters: wave64 transcendentals ~16cy => R2 is
// trans-bound (16 trans/elem ~ 17us > 14us HBM floor).
//
// Round 6: R2 structure + Pade(4) tanh(z) ~= z(105+10u)/(105+45u+u^2), u=z^2,
// clamp |z|<=3.2 (max err 0.0053 in-range, <=0.0104 tail; worst-case output
// err ~0.03 << 0.108 threshold), with quad-batched reciprocals (Montgomery:
// 1 v_rcp per 4 denominators). Per element: 16 trans -> 2 trans.

#define HGEO 8

__global__ __launch_bounds__(256) void geodesic_kernel(
    const float4* __restrict__ c_target,
    const float4* __restrict__ wavelength,
    const float4* __restrict__ A_source,
    const float* __restrict__ W1,   // [8][3] row-major
    const float* __restrict__ b1,   // [8]
    const float* __restrict__ W2,   // [8]
    const float* __restrict__ b2,   // [1]
    float4* __restrict__ out)
{
    // Uniform params -> scalar regs. Fold W2 into the Pade numerator coeffs.
    float wa[HGEO], wb[HGEO], bb[HGEO], n0[HGEO], n1[HGEO];
    const float bias2 = b2[0];
#pragma unroll
    for (int j = 0; j < HGEO; ++j) {
        wa[j] = W1[j * 3 + 0];
        wb[j] = W1[j * 3 + 1];
        bb[j] = b1[j];
        float wo = W2[j];
        n0[j] = 105.0f * wo;
        n1[j] = 10.0f * wo;
    }

    const int i = blockIdx.x * blockDim.x + threadIdx.x;

    float4 c = c_target[i];
    float4 w = wavelength[i];
    float4 a = A_source[i];

    const float cv[4] = {c.x, c.y, c.z, c.w};
    const float wv[4] = {w.x, w.y, w.z, w.w};
    const float av[4] = {a.x, a.y, a.z, a.w};
    float ov[4];

#pragma unroll
    for (int k = 0; k < 4; ++k) {
        float s = av[k] + bias2;
        float num[HGEO], den[HGEO];
#pragma unroll
        for (int j = 0; j < HGEO; ++j) {
            float z = fmaf(wa[j], cv[k], fmaf(wb[j], wv[k], bb[j]));
            z = fminf(fmaxf(z, -3.2f), 3.2f);          // -> v_med3_f32
            float u = z * z;
            num[j] = z * fmaf(n1[j], u, n0[j]);        // wo * z * (105 + 10u)
            den[j] = fmaf(u, u, fmaf(u, 45.0f, 105.0f)); // u^2 + 45u + 105 >= 105
        }
        // Quad-batched reciprocals: 1 v_rcp per 4 denominators.
#pragma unroll
        for (int g = 0; g < 2; ++g) {
            const int b = g * 4;
            float p01 = den[b + 0] * den[b + 1];
            float p23 = den[b + 2] * den[b + 3];
            float r   = __builtin_amdgcn_rcpf(p01 * p23);
            float r01 = p23 * r;   // 1/(den0*den1)
            float r23 = p01 * r;   // 1/(den2*den3)
            s = fmaf(num[b + 0], den[b + 1] * r01, s);
            s = fmaf(num[b + 1], den[b + 0] * r01, s);
            s = fmaf(num[b + 2], den[b + 3] * r23, s);
            s = fmaf(num[b + 3], den[b + 2] * r23, s);
        }
        ov[k] = s;
    }
    out[i] = make_float4(ov[0], ov[1], ov[2], ov[3]);
}

extern "C" void kernel_launch(void* const* d_in, const int* in_sizes, int n_in,
                              void* d_out, int out_size, void* d_ws, size_t ws_size,
                              hipStream_t stream) {
    // Input order per setup_inputs(): c_source, c_target, wavelength, A_source, W1, b1, W2, b2
    const float4* c_target   = (const float4*)d_in[1];
    const float4* wavelength = (const float4*)d_in[2];
    const float4* A_source   = (const float4*)d_in[3];
    const float*  W1 = (const float*)d_in[4];
    const float*  b1 = (const float*)d_in[5];
    const float*  W2 = (const float*)d_in[6];
    const float*  b2 = (const float*)d_in[7];
    float4* out = (float4*)d_out;

    const int n4 = out_size / 4;                 // 2097152 float4s
    const int threads = 256;
    const int blocks = n4 / threads;             // 8192 — exact, 1 float4/thread
    geodesic_kernel<<<blocks, threads, 0, stream>>>(
        c_target, wavelength, A_source, W1, b1, W2, b2, out);
}